// Round 14
// baseline (114.740 us; speedup 1.0000x reference)
//
#include <hip/hip_runtime.h>
#include <math.h>

#define CIN   16
#define COUT  64
#define H     256
#define W     256
#define OH    254
#define OW    254
#define NTAP  9
#define HWSZ  (H * W)

typedef _Float16 f16x8  __attribute__((ext_vector_type(8)));
typedef float    f32x16 __attribute__((ext_vector_type(16)));

// weight pack: [tap 9][msub 2][lane 64][e 8] fp16; co=(l&31)+32m, cin=8*(l>>5)+e
__global__ void wpack_kernel(const float* __restrict__ w, _Float16* __restrict__ wpk) {
    int idx = blockIdx.x * 256 + threadIdx.x;   // 0..9215
    if (idx >= NTAP * 2 * 64 * 8) return;
    int e = idx & 7, l = (idx >> 3) & 63, m = (idx >> 9) & 1, t = idx >> 10;
    int co  = (l & 31) + 32 * m;
    int cin = 8 * (l >> 5) + e;
    wpk[idx] = (_Float16)w[((co * CIN + cin) * 3 + t / 3) * 3 + (t % 3)];
}

__device__ __forceinline__ float tanh_fast(float v) {
    float e = __expf(2.0f * v);
    return 1.0f - 2.0f * __builtin_amdgcn_rcpf(e + 1.0f);
}
__device__ __forceinline__ float min3f(float a, float b, float c) {
    return fminf(fminf(a, b), c);   // clang fuses to v_min3_f32
}

// 128 thr = 2 waves; wave m computes couts [32m, 32m+32) for a 32-px column.
// Block marches 64 rows, 1 out row/iter, ring=4 input rows, 1 barrier/iter.
// Register diet (wreg 36, acc 16, cbias 16) -> 4 waves/SIMD, 8 blocks/CU.
__global__ __launch_bounds__(128, 4) void conv_mfma_kernel(
        const float* __restrict__ x, const f16x8* __restrict__ wpk,
        const float* __restrict__ bias, float* __restrict__ out) {
    __shared__ f16x8 ring[4 * 72];        // 4 rows x (2 g x 36 px) = 4,608 B
    __shared__ float xpart[2][2][32];     // [iter parity][m][px] exchange

    const int tid   = threadIdx.x;
    const int lane  = tid & 63;
    const int wavem = tid >> 6;           // cout half this wave owns

    int bid = blockIdx.x;
    int nb  = (bid & 7) * 256 + (bid >> 3);   // 2048 = 8*256 bijective XCD swizzle
    const int img   = nb >> 5;
    const int rem   = nb & 31;
    const int slice = rem & 7;            // 32-px column
    const int strip = rem >> 3;           // 64-row strip
    const int P0    = slice * 32;
    const int r0    = strip * 64;

    // wave's cin-half base (staging reads cin 8*wavem .. +7)
    const float* xb = x + (size_t)img * CIN * HWSZ + (size_t)(8 * wavem) * HWSZ;

    // ---- weights: this wave's m-half only -> 36 VGPRs ----
    f16x8 wreg[NTAP];
#pragma unroll
    for (int t = 0; t < NTAP; ++t)
        wreg[t] = wpk[(t * 2 + wavem) * 64 + lane];

    const int l31 = lane & 31;
    const int g2  = lane >> 5;

    // bias C-fragment (m-half): col=l31(px), row=(q&3)+8*(q>>2)+4*g2+32m
    f32x16 cbias;
#pragma unroll
    for (int q = 0; q < 16; ++q)
        cbias[q] = bias[(q & 3) + 8 * (q >> 2) + 4 * g2 + 32 * wavem];

    const int roff0 = g2 * 36 + l31;      // frag slot for kw=0 (+1,+2 for kw=1,2)

    // staging: lanes 0..17 of each wave; wave m stages cin 8m..8m+7,
    // px pair {2*lane, 2*lane+1} of the 36-px window [P0, P0+36)
    int spx = P0 + 2 * lane;
    if (spx > 254) spx = 254;             // in-bounds; only feeds masked outputs
    const float* xcol = xb + spx;

    float2 vv[8];

#define SLOAD(rowAbs)                                                           \
    if (lane < 18) {                                                            \
        int g_ = (rowAbs); if (g_ > 255) g_ = 255;                              \
        const float* p_ = xcol + (size_t)g_ * W;                                \
        _Pragma("unroll")                                                       \
        for (int c = 0; c < 8; ++c) vv[c] = *(const float2*)(p_ + (size_t)c * HWSZ); \
    }

#define SWRITE(slot)                                                            \
    if (lane < 18) {                                                            \
        f16x8 q0, q1;                                                           \
        _Pragma("unroll")                                                       \
        for (int c = 0; c < 8; ++c) { q0[c] = (_Float16)vv[c].x;                \
                                      q1[c] = (_Float16)vv[c].y; }              \
        int b_ = (slot) * 72 + wavem * 36 + 2 * lane;                           \
        ring[b_]     = q0;                                                      \
        ring[b_ + 1] = q1;                                                      \
    }

    // ---- prologue: rows r0..r0+2 -> slots 0..2; row r0+3 left in flight ----
    SLOAD(r0 + 0) SWRITE(0)
    SLOAD(r0 + 1) SWRITE(1)
    SLOAD(r0 + 2) SWRITE(2)
    SLOAD(r0 + 3)
    __syncthreads();

    const size_t obase = (size_t)img * OH * OW;

#pragma unroll 1
    for (int i = 0; i < 64; ++i) {
        // 1. MFMA phase: rows i..i+2, 9 frag reads -> 9 chained MFMAs
        f32x16 acc;
        {
            const f16x8* xr = &ring[((i + 0) & 3) * 72];
            f16x8 f0 = xr[roff0], f1 = xr[roff0 + 1], f2 = xr[roff0 + 2];
            acc = __builtin_amdgcn_mfma_f32_32x32x16_f16(wreg[0], f0, cbias, 0, 0, 0);
            acc = __builtin_amdgcn_mfma_f32_32x32x16_f16(wreg[1], f1, acc, 0, 0, 0);
            acc = __builtin_amdgcn_mfma_f32_32x32x16_f16(wreg[2], f2, acc, 0, 0, 0);
        }
#pragma unroll
        for (int kh = 1; kh < 3; ++kh) {
            const f16x8* xr = &ring[((i + kh) & 3) * 72];
            f16x8 f0 = xr[roff0], f1 = xr[roff0 + 1], f2 = xr[roff0 + 2];
            acc = __builtin_amdgcn_mfma_f32_32x32x16_f16(wreg[3 * kh + 0], f0, acc, 0, 0, 0);
            acc = __builtin_amdgcn_mfma_f32_32x32x16_f16(wreg[3 * kh + 1], f1, acc, 0, 0, 0);
            acc = __builtin_amdgcn_mfma_f32_32x32x16_f16(wreg[3 * kh + 2], f2, acc, 0, 0, 0);
        }

        // 2. publish input row i+3 (slot of row i-1: both waves past its reads)
        SWRITE((i + 3) & 3)

        // 3. partial min over this wave's 32 couts
        float mn = fminf(acc[0], acc[1]);
#pragma unroll
        for (int q = 2; q < 16; q += 2) mn = min3f(acc[q], acc[q + 1], mn);
        mn = fminf(mn, __shfl_xor(mn, 32));
        if (lane < 32) xpart[i & 1][wavem][lane] = mn;

        // 4. one barrier: orders ring publish + exchange (no vmem outstanding)
        __syncthreads();

        // 5. wave0 combines halves, tanh(tanh), stores
        if (wavem == 0 && lane < 32) {
            float o = fminf(mn, xpart[i & 1][1][lane]);
            o = tanh_fast(tanh_fast(o));
            const int oh = r0 + i, px = P0 + lane;
            if (oh < OH && px < OW) out[obase + (size_t)oh * OW + px] = o;
        }

        // 6. issue loads for row i+4 AFTER the barrier (no drain catches them)
        SLOAD(r0 + i + 4)
    }
}

extern "C" void kernel_launch(void* const* d_in, const int* in_sizes, int n_in,
                              void* d_out, int out_size, void* d_ws, size_t ws_size,
                              hipStream_t stream) {
    const float* x    = (const float*)d_in[0];
    const float* w    = (const float*)d_in[1];
    const float* bias = (const float*)d_in[2];
    float* out = (float*)d_out;
    _Float16* wpk = (_Float16*)d_ws;   // 9216 fp16 = 18,432 B

    wpack_kernel<<<36, 256, 0, stream>>>(w, wpk);
    conv_mfma_kernel<<<2048, 128, 0, stream>>>(x, (const f16x8*)wpk, bias, out);
}